// Round 5
// baseline (19.446 us; speedup 1.0000x reference)
//
#include <hip/hip_runtime.h>
#include <math.h>

// Reference collapses (softmax over size-1 axis == 1) to:
//   s[b,n] = sum_k x[b,k] * W'[k,n]   (M=256, N=160, K=9216)
//   W'[p*8+j][d*16+i] = W[p][d][i][j]; then squash over 16-groups of n.
// bf16 MFMA path (threshold 1.5e-2 >> bf16 error ~4e-3).
#define M 256
#define N 160
#define K 9216
#define CH 72     // k-chunks
#define KC 128    // k per chunk = 16 p
#define BM 64

using f32x4 = __attribute__((ext_vector_type(4))) float;
using bf16x8 = __attribute__((ext_vector_type(8))) short;

__device__ __forceinline__ ushort f2bf(float f) {
  uint u = __builtin_bit_cast(uint, f);
  u += 0x7FFF + ((u >> 16) & 1);  // RNE
  return (ushort)(u >> 16);
}

// grid = 288 blocks (8 XCD * 36), 256 thr (4 waves).
// XCD-aware map: chunk c's 4 m-tiles land on ONE XCD -> W L2-reuse.
// A-frags straight from global (no X LDS); W staged once per block.
template <bool ATOMIC>
__global__ __launch_bounds__(256) void gemm_mfma(const float* __restrict__ x,
                                                 const float* __restrict__ W,
                                                 float* __restrict__ part) {
  __shared__ ushort Wl[N * KC];  // [n][k] bf16 (W' transposed), XOR-swizzled

  const int t = threadIdx.x;
  const int bx = blockIdx.x;
  const int xcd = bx & 7;
  const int idx = bx >> 3;            // 0..35
  const int c = xcd * 9 + (idx >> 2); // 0..71, 4 consecutive blocks share c
  const int mt = idx & 3;
  const int m0 = mt * BM;
  const int k0 = c * KC;

  const int w = t >> 6;
  const int l = t & 63;
  const int lr = l & 15;
  const int lg = l >> 4;

  // ---- A fragments: direct global loads (issued before barrier) ----
  const float* xr = x + (size_t)(m0 + w * 16 + lr) * K + k0;
  float4 araw[4][2];
#pragma unroll
  for (int ks = 0; ks < 4; ++ks) {
    araw[ks][0] = *(const float4*)(xr + ks * 32 + lg * 8);
    araw[ks][1] = *(const float4*)(xr + ks * 32 + lg * 8 + 4);
  }

  // ---- stage W chunk: 16 p = 20480 f32, transposed to [n][k] bf16 ----
  {
    const float* ws = W + (size_t)(c * 16) * 1280;
#pragma unroll
    for (int q = 0; q < 20; ++q) {
      const int f = t + 256 * q;  // float4 idx < 5120
      const float4 v = *(const float4*)(ws + 4 * (size_t)f);
      const int pl = f / 320;     // p-local (320 float4 per p)
      const int r = f - pl * 320;
      const int d = r >> 5;
      const int idx2 = r & 31;
      const int i = idx2 >> 1;
      const int j = (idx2 & 1) << 2;  // 0 or 4
      const int n = d * 16 + i;
      const int kk = pl * 8 + j;
      ushort4 h = {f2bf(v.x), f2bf(v.y), f2bf(v.z), f2bf(v.w)};
      const int E = (n * KC + kk) ^ ((n & 7) << 3);
      *(ushort4*)&Wl[E] = h;
    }
  }

  // convert A while W loads drain
  bf16x8 af[4];
#pragma unroll
  for (int ks = 0; ks < 4; ++ks) {
    af[ks][0] = (short)f2bf(araw[ks][0].x);
    af[ks][1] = (short)f2bf(araw[ks][0].y);
    af[ks][2] = (short)f2bf(araw[ks][0].z);
    af[ks][3] = (short)f2bf(araw[ks][0].w);
    af[ks][4] = (short)f2bf(araw[ks][1].x);
    af[ks][5] = (short)f2bf(araw[ks][1].y);
    af[ks][6] = (short)f2bf(araw[ks][1].z);
    af[ks][7] = (short)f2bf(araw[ks][1].w);
  }
  __syncthreads();

  // ---- MFMA: 4 k-steps x 10 n-tiles ----
  f32x4 acc[10];
#pragma unroll
  for (int nt = 0; nt < 10; ++nt) acc[nt] = {0.f, 0.f, 0.f, 0.f};

#pragma unroll
  for (int ks = 0; ks < 4; ++ks) {
#pragma unroll
    for (int nt = 0; nt < 10; ++nt) {
      const int n = nt * 16 + lr;
      const int EB = (n * KC + ks * 32 + lg * 8) ^ ((n & 7) << 3);
      const bf16x8 b = *(const bf16x8*)&Wl[EB];
      acc[nt] =
          __builtin_amdgcn_mfma_f32_16x16x32_bf16(af[ks], b, acc[nt], 0, 0, 0);
    }
  }

  // ---- store: C row = (lane>>4)*4 + reg, col = lane&15 ----
  if (ATOMIC) {
#pragma unroll
    for (int nt = 0; nt < 10; ++nt)
#pragma unroll
      for (int r = 0; r < 4; ++r) {
        const int row = m0 + w * 16 + lg * 4 + r;
        atomicAdd(&part[(size_t)row * N + nt * 16 + lr], acc[nt][r]);
      }
  } else {
    float* dst = part + (size_t)c * (M * N);
#pragma unroll
    for (int nt = 0; nt < 10; ++nt)
#pragma unroll
      for (int r = 0; r < 4; ++r) {
        const int row = m0 + w * 16 + lg * 4 + r;
        dst[(size_t)row * N + nt * 16 + lr] = acc[nt][r];
      }
  }
}

// Vectorized reduce + squash. grid = 40960/256 = 160 blocks, 256 thr.
// Thread: one float4 of outputs x 1/4 of the 72 chunks.
__global__ __launch_bounds__(256) void reduce_squash4(
    const float* __restrict__ part, float* __restrict__ out) {
  __shared__ f32x4 red[256];
  const int t = threadIdx.x;
  const int o4 = t & 63;        // float4 index within block's 256 outputs
  const int slice = t >> 6;     // 0..3, 18 chunks each
  const f32x4* p4 = (const f32x4*)part;
  const int base4 = blockIdx.x * 64;

  f32x4 sum = {0.f, 0.f, 0.f, 0.f};
#pragma unroll 6
  for (int cc = 0; cc < 18; ++cc) {
    const int c = slice * 18 + cc;
    sum += p4[(size_t)c * (M * N / 4) + base4 + o4];
  }
  red[t] = sum;
  __syncthreads();
  if (t < 64) {
    const f32x4 s = red[t] + red[t + 64] + red[t + 128] + red[t + 192];
    float n2 = s[0] * s[0] + s[1] * s[1] + s[2] * s[2] + s[3] * s[3];
    n2 += __shfl_xor(n2, 1);    // quad = one 16-elem group
    n2 += __shfl_xor(n2, 2);
    const float sc = n2 / (1.0f + n2) / sqrtf(n2 + 1e-9f);
    f32x4 o = {s[0] * sc, s[1] * sc, s[2] * sc, s[3] * sc};
    ((f32x4*)out)[base4 + t] = o;
  }
}

__global__ __launch_bounds__(256) void squash_k(float* __restrict__ out) {
  const int e = blockIdx.x * 256 + threadIdx.x;
  const float s = out[e];
  float s2 = s * s;
  s2 += __shfl_xor(s2, 1);
  s2 += __shfl_xor(s2, 2);
  s2 += __shfl_xor(s2, 4);
  s2 += __shfl_xor(s2, 8);
  out[e] = s * s2 / (1.0f + s2) / sqrtf(s2 + 1e-9f);
}

extern "C" void kernel_launch(void* const* d_in, const int* in_sizes, int n_in,
                              void* d_out, int out_size, void* d_ws,
                              size_t ws_size, hipStream_t stream) {
  const float* x = (const float*)d_in[0];  // [256,1152,8,1]
  const float* W = (const float*)d_in[1];  // [1152,10,16,8]
  float* out = (float*)d_out;              // [256,10,16,1] = 40960 f32

  const size_t need = (size_t)CH * M * N * sizeof(float);  // 11.8 MB
  if (ws_size >= need) {
    gemm_mfma<false><<<4 * CH, 256, 0, stream>>>(x, W, (float*)d_ws);
    reduce_squash4<<<(M * N) / 256, 256, 0, stream>>>((const float*)d_ws, out);
  } else {
    hipMemsetAsync(out, 0, (size_t)M * N * sizeof(float), stream);
    gemm_mfma<true><<<4 * CH, 256, 0, stream>>>(x, W, out);
    squash_k<<<(M * N) / 256, 256, 0, stream>>>(out);
  }
}